// Round 2
// baseline (394.967 us; speedup 1.0000x reference)
//
#include <hip/hip_runtime.h>
#include <stdint.h>

#define T_TOK   4096
#define D_MODEL 768
#define F_FF    3072
#define N_EXP   8
#define BM      128
#define MAX_TILES 40
#define MCAP    (MAX_TILES * BM)   // 5120 padded rows capacity

typedef __attribute__((ext_vector_type(4))) float  floatx4;
typedef __attribute__((ext_vector_type(8))) short  short8;

__device__ __forceinline__ unsigned short f2bf(float f) {
    union { float f; unsigned int u; } v; v.f = f;
    unsigned int u = v.u;
    unsigned int r = (u + 0x7FFFu + ((u >> 16) & 1u)) >> 16;  // RNE
    return (unsigned short)r;
}

// ---------------- router: one wave per token ----------------
__global__ __launch_bounds__(256) void router_kernel(
        const float* __restrict__ x, const float* __restrict__ wsw,
        const float* __restrict__ bsw, int* __restrict__ routes,
        int* __restrict__ cnt, float* __restrict__ rps) {
    __shared__ float srps[N_EXP];
    __shared__ int   scnt[N_EXP];
    int tid = threadIdx.x;
    if (tid < N_EXP) { srps[tid] = 0.f; scnt[tid] = 0; }
    __syncthreads();
    int wave = tid >> 6, l = tid & 63;
    int t = blockIdx.x * 4 + wave;
    const float* xr = x + (size_t)t * D_MODEL;
    double acc[N_EXP];
#pragma unroll
    for (int e = 0; e < N_EXP; e++) acc[e] = 0.0;
    for (int d = l; d < D_MODEL; d += 64) {
        float xv = xr[d];
        const float* wr = wsw + d * N_EXP;
#pragma unroll
        for (int e = 0; e < N_EXP; e++) acc[e] += (double)xv * (double)wr[e];
    }
#pragma unroll
    for (int off = 32; off > 0; off >>= 1) {
#pragma unroll
        for (int e = 0; e < N_EXP; e++) acc[e] += __shfl_xor(acc[e], off, 64);
    }
    if (l == 0) {
        float logit[N_EXP];
        float mx = -1e30f; int am = 0;
#pragma unroll
        for (int e = 0; e < N_EXP; e++) {
            logit[e] = (float)acc[e] + bsw[e];
            if (logit[e] > mx) { mx = logit[e]; am = e; }
        }
        float p[N_EXP]; float s = 0.f;
#pragma unroll
        for (int e = 0; e < N_EXP; e++) { p[e] = __expf(logit[e] - mx); s += p[e]; }
        float inv = 1.f / s;
        routes[t] = am;
        atomicAdd(&scnt[am], 1);
#pragma unroll
        for (int e = 0; e < N_EXP; e++) atomicAdd(&srps[e], p[e] * inv);
    }
    __syncthreads();
    if (tid < N_EXP) {
        atomicAdd(&cnt[tid], scnt[tid]);
        atomicAdd(&rps[tid], srps[tid]);
    }
}

// ---------------- plan: offsets, tile table, output tail ----------------
__global__ void plan_kernel(const int* __restrict__ cnt, const float* __restrict__ rps,
                            int* __restrict__ astart, int* __restrict__ cursor,
                            int* __restrict__ tile_e, int* __restrict__ tile_m0,
                            float* __restrict__ out_tail) {
    if (threadIdx.x == 0 && blockIdx.x == 0) {
        int a = 0, idx = 0;
        for (int e = 0; e < N_EXP; e++) {
            astart[e] = a; cursor[e] = a;
            int nt = (cnt[e] + BM - 1) / BM;
            for (int j = 0; j < nt; j++) { tile_e[idx] = e; tile_m0[idx] = a + j * BM; idx++; }
            a += nt * BM;
        }
        for (; idx < MAX_TILES; idx++) { tile_e[idx] = -1; tile_m0[idx] = 0; }
        for (int e = 0; e < N_EXP; e++) {
            out_tail[e] = (float)cnt[e];
            out_tail[N_EXP + e] = rps[e];
        }
        out_tail[2 * N_EXP] = 0.0f;   // n_dropped = 0
    }
}

// ---------------- fused scatter + gather/cast: one wave per token ----------------
__global__ __launch_bounds__(256) void scatter_gather_kernel(
        const float* __restrict__ x, const int* __restrict__ routes,
        int* __restrict__ cursor, int* __restrict__ perm,
        unsigned short* __restrict__ Xs) {
    int wave = threadIdx.x >> 6, l = threadIdx.x & 63;
    int t = blockIdx.x * 4 + wave;
    int pos = 0;
    if (l == 0) {
        int e = routes[t];
        pos = atomicAdd(&cursor[e], 1);
        perm[pos] = t;
    }
    pos = __shfl(pos, 0, 64);
    const float4* src = (const float4*)(x + (size_t)t * D_MODEL);
    ushort4* dst = (ushort4*)(Xs + (size_t)pos * D_MODEL);
#pragma unroll
    for (int i = 0; i < 3; i++) {
        float4 v = src[i * 64 + l];
        ushort4 o;
        o.x = f2bf(v.x); o.y = f2bf(v.y); o.z = f2bf(v.z); o.w = f2bf(v.w);
        dst[i * 64 + l] = o;
    }
}

// ---------------- transpose + cast fp32 [R][C] -> bf16 [C][R], per expert ----------------
__global__ __launch_bounds__(256) void transpose_cast_kernel(
        const float* __restrict__ src, unsigned short* __restrict__ dst, int R, int C) {
    __shared__ float tile[64][65];
    int e = blockIdx.z;
    const float* s = src + (size_t)e * R * C;
    unsigned short* d = dst + (size_t)e * R * C;
    int tx = threadIdx.x & 63;
    int ty = threadIdx.x >> 6;            // 0..3
    int c0 = blockIdx.x * 64, r0 = blockIdx.y * 64;
#pragma unroll
    for (int k = 0; k < 16; k++) {
        int r = ty + k * 4;
        tile[r][tx] = s[(size_t)(r0 + r) * C + (c0 + tx)];
    }
    __syncthreads();
#pragma unroll
    for (int k = 0; k < 16; k++) {
        int c = ty + k * 4;
        ushort2 v;
        v.x = f2bf(tile[tx * 2][c]);
        v.y = f2bf(tile[tx * 2 + 1][c]);
        *(ushort2*)(&d[(size_t)(c0 + c) * R + (r0 + tx * 2)]) = v;
    }
}

// ---------------- GEMM1: 128x128x32 bf16 MFMA, relu -> bf16 out ----------------
// A: Xs [MCAP][768].  Bt: Wt [E][3072][768].  C: Y1 [MCAP][3072] bf16.
__global__ __launch_bounds__(256) void gemm1_kernel(
        const unsigned short* __restrict__ A, const unsigned short* __restrict__ Bt,
        const int* __restrict__ tile_e, const int* __restrict__ tile_m0,
        unsigned short* __restrict__ Obf) {
    const int K = D_MODEL, N = F_FF;
    int e = tile_e[blockIdx.y];
    if (e < 0) return;
    int m0 = tile_m0[blockIdx.y];
    int n0 = blockIdx.x * 128;
    const unsigned short* Be = Bt + (size_t)e * N * K;

    __shared__ __align__(16) unsigned short ldsA[128 * 32];
    __shared__ __align__(16) unsigned short ldsB[128 * 32];

    int tid = threadIdx.x;
    int w = tid >> 6, l = tid & 63;
    int wm = w & 1, wn = w >> 1;
    int quad = l >> 4, l15 = l & 15;

    floatx4 zero = {0.f, 0.f, 0.f, 0.f};
    floatx4 acc[4][4];
#pragma unroll
    for (int i = 0; i < 4; i++)
#pragma unroll
        for (int j = 0; j < 4; j++) acc[i][j] = zero;

    int r0 = w * 16 + (l >> 2);
    int cb = (l & 3) * 16;
    const char* gA = (const char*)(A + (size_t)(m0 + r0) * K) + cb;
    const char* gB = (const char*)(Be + (size_t)(n0 + r0) * K) + cb;
    char* lA = (char*)ldsA + w * 1024;
    char* lB = (char*)ldsB + w * 1024;
    const size_t rowskip = (size_t)64 * K * 2;

#pragma unroll 1
    for (int kc = 0; kc < K; kc += 32) {
        const char* ga = gA + kc * 2;
        const char* gb = gB + kc * 2;
        __builtin_amdgcn_global_load_lds((const __attribute__((address_space(1))) unsigned int*)ga,
                                         (__attribute__((address_space(3))) unsigned int*)lA, 16, 0, 0);
        __builtin_amdgcn_global_load_lds((const __attribute__((address_space(1))) unsigned int*)(ga + rowskip),
                                         (__attribute__((address_space(3))) unsigned int*)(lA + 4096), 16, 0, 0);
        __builtin_amdgcn_global_load_lds((const __attribute__((address_space(1))) unsigned int*)gb,
                                         (__attribute__((address_space(3))) unsigned int*)lB, 16, 0, 0);
        __builtin_amdgcn_global_load_lds((const __attribute__((address_space(1))) unsigned int*)(gb + rowskip),
                                         (__attribute__((address_space(3))) unsigned int*)(lB + 4096), 16, 0, 0);
        __syncthreads();

        short8 af[4], bf[4];
#pragma unroll
        for (int i = 0; i < 4; i++)
            af[i] = *(const short8*)(ldsA + (wm * 64 + i * 16 + l15) * 32 + quad * 8);
#pragma unroll
        for (int j = 0; j < 4; j++)
            bf[j] = *(const short8*)(ldsB + (wn * 64 + j * 16 + l15) * 32 + quad * 8);
#pragma unroll
        for (int i = 0; i < 4; i++)
#pragma unroll
            for (int j = 0; j < 4; j++)
                acc[i][j] = __builtin_amdgcn_mfma_f32_16x16x32_bf16(af[i], bf[j], acc[i][j], 0, 0, 0);
        __syncthreads();
    }

#pragma unroll
    for (int i = 0; i < 4; i++) {
#pragma unroll
        for (int r = 0; r < 4; r++) {
            int row = m0 + wm * 64 + i * 16 + quad * 4 + r;
            size_t base = (size_t)row * N + n0 + wn * 64 + l15;
#pragma unroll
            for (int j = 0; j < 4; j++) {
                float v = acc[i][j][r];
                v = v > 0.f ? v : 0.f;
                Obf[base + j * 16] = f2bf(v);
            }
        }
    }
}

// ---------------- GEMM2: split-K=4, fp32 atomic scatter into out ----------------
// A: Y1 [MCAP][3072].  Bt: Wt [E][768][3072].  C += into out[token][768].
// 1D grid 960: bid = m_idx*24 + strip, strip = ks*6 + n_idx.
// Same-strip blocks spaced 24 (== 0 mod 8) apart -> same XCD -> B-strip L2 reuse.
__global__ __launch_bounds__(256) void gemm2_kernel(
        const unsigned short* __restrict__ A, const unsigned short* __restrict__ Bt,
        const int* __restrict__ tile_e, const int* __restrict__ tile_m0,
        const int* __restrict__ perm, float* __restrict__ Of32) {
    const int K = F_FF, N = D_MODEL, KQ = F_FF / 4;
    int bid = blockIdx.x;
    int strip = bid % 24;
    int m_idx = bid / 24;
    int e = tile_e[m_idx];
    if (e < 0) return;
    int m0 = tile_m0[m_idx];
    int ks = strip / 6;
    int n0 = (strip % 6) * 128;
    const unsigned short* Be = Bt + (size_t)e * N * K;

    __shared__ __align__(16) unsigned short ldsA[128 * 32];
    __shared__ __align__(16) unsigned short ldsB[128 * 32];

    int tid = threadIdx.x;
    int w = tid >> 6, l = tid & 63;
    int wm = w & 1, wn = w >> 1;
    int quad = l >> 4, l15 = l & 15;

    floatx4 zero = {0.f, 0.f, 0.f, 0.f};
    floatx4 acc[4][4];
#pragma unroll
    for (int i = 0; i < 4; i++)
#pragma unroll
        for (int j = 0; j < 4; j++) acc[i][j] = zero;

    int r0 = w * 16 + (l >> 2);
    int cb = (l & 3) * 16;
    const char* gA = (const char*)(A + (size_t)(m0 + r0) * K) + cb;
    const char* gB = (const char*)(Be + (size_t)(n0 + r0) * K) + cb;
    char* lA = (char*)ldsA + w * 1024;
    char* lB = (char*)ldsB + w * 1024;
    const size_t rowskip = (size_t)64 * K * 2;

    int k_lo = ks * KQ, k_hi = k_lo + KQ;
#pragma unroll 1
    for (int kc = k_lo; kc < k_hi; kc += 32) {
        const char* ga = gA + kc * 2;
        const char* gb = gB + kc * 2;
        __builtin_amdgcn_global_load_lds((const __attribute__((address_space(1))) unsigned int*)ga,
                                         (__attribute__((address_space(3))) unsigned int*)lA, 16, 0, 0);
        __builtin_amdgcn_global_load_lds((const __attribute__((address_space(1))) unsigned int*)(ga + rowskip),
                                         (__attribute__((address_space(3))) unsigned int*)(lA + 4096), 16, 0, 0);
        __builtin_amdgcn_global_load_lds((const __attribute__((address_space(1))) unsigned int*)gb,
                                         (__attribute__((address_space(3))) unsigned int*)lB, 16, 0, 0);
        __builtin_amdgcn_global_load_lds((const __attribute__((address_space(1))) unsigned int*)(gb + rowskip),
                                         (__attribute__((address_space(3))) unsigned int*)(lB + 4096), 16, 0, 0);
        __syncthreads();

        short8 af[4], bf[4];
#pragma unroll
        for (int i = 0; i < 4; i++)
            af[i] = *(const short8*)(ldsA + (wm * 64 + i * 16 + l15) * 32 + quad * 8);
#pragma unroll
        for (int j = 0; j < 4; j++)
            bf[j] = *(const short8*)(ldsB + (wn * 64 + j * 16 + l15) * 32 + quad * 8);
#pragma unroll
        for (int i = 0; i < 4; i++)
#pragma unroll
            for (int j = 0; j < 4; j++)
                acc[i][j] = __builtin_amdgcn_mfma_f32_16x16x32_bf16(af[i], bf[j], acc[i][j], 0, 0, 0);
        __syncthreads();
    }

#pragma unroll
    for (int i = 0; i < 4; i++) {
#pragma unroll
        for (int r = 0; r < 4; r++) {
            int row = m0 + wm * 64 + i * 16 + quad * 4 + r;
            int t = perm[row];
            if (t < 0) continue;
            size_t base = (size_t)t * N + n0 + wn * 64 + l15;
#pragma unroll
            for (int j = 0; j < 4; j++)
                atomicAdd(&Of32[base + j * 16], acc[i][j][r]);
        }
    }
}

extern "C" void kernel_launch(void* const* d_in, const int* in_sizes, int n_in,
                              void* d_out, int out_size, void* d_ws, size_t ws_size,
                              hipStream_t stream) {
    const float* x   = (const float*)d_in[0];
    const float* wsw = (const float*)d_in[1];
    const float* bsw = (const float*)d_in[2];
    const float* wi  = (const float*)d_in[3];
    const float* wo  = (const float*)d_in[4];
    float* out = (float*)d_out;

    char* ws = (char*)d_ws;
    int*   cnt     = (int*)(ws + 0);      // 8 ints
    float* rps     = (float*)(ws + 64);   // 8 floats
    int*   cursor  = (int*)(ws + 128);
    int*   astart  = (int*)(ws + 192);
    int*   tile_e  = (int*)(ws + 256);    // 40 ints
    int*   tile_m0 = (int*)(ws + 512);    // 40 ints
    int*   perm    = (int*)(ws + 1024);                 // MCAP ints -> ends 21504
    int*   routes  = (int*)(ws + 1024 + MCAP * 4);      // 4096 ints -> ends 37888
    unsigned short* Xs = (unsigned short*)(ws + 37888);             // 5120*768*2  = 7,864,320
    unsigned short* Y1 = (unsigned short*)(ws + 7902208);           // 5120*3072*2 = 31,457,280
    unsigned short* Wt = (unsigned short*)(ws + 39359488);          // 8*3072*768*2 = 37,748,736

    hipMemsetAsync(ws, 0, 1024, stream);
    hipMemsetAsync(ws + 1024, 0xFF, MCAP * 4, stream);               // perm = -1
    hipMemsetAsync(out, 0, (size_t)T_TOK * D_MODEL * 4, stream);     // atomic target

    router_kernel<<<T_TOK / 4, 256, 0, stream>>>(x, wsw, bsw, routes, cnt, rps);
    plan_kernel<<<1, 64, 0, stream>>>(cnt, rps, astart, cursor, tile_e, tile_m0,
                                      out + (size_t)T_TOK * D_MODEL);
    scatter_gather_kernel<<<T_TOK / 4, 256, 0, stream>>>(x, routes, cursor, perm, Xs);

    // wi [E][D][F] -> Wt [E][F][D]
    transpose_cast_kernel<<<dim3(F_FF / 64, D_MODEL / 64, N_EXP), 256, 0, stream>>>(wi, Wt, D_MODEL, F_FF);
    gemm1_kernel<<<dim3(F_FF / 128, MAX_TILES), 256, 0, stream>>>(Xs, Wt, tile_e, tile_m0, Y1);

    // wo [E][F][D] -> Wt [E][D][F]
    transpose_cast_kernel<<<dim3(D_MODEL / 64, F_FF / 64, N_EXP), 256, 0, stream>>>(wo, Wt, F_FF, D_MODEL);
    gemm2_kernel<<<24 * MAX_TILES, 256, 0, stream>>>(Y1, Wt, tile_e, tile_m0, perm, out);
}

// Round 3
// 359.468 us; speedup vs baseline: 1.0988x; 1.0988x over previous
//
#include <hip/hip_runtime.h>
#include <stdint.h>

#define T_TOK   4096
#define D_MODEL 768
#define F_FF    3072
#define N_EXP   8
#define BM      128
#define MAX_TILES 40
#define MCAP    (MAX_TILES * BM)   // 5120 padded rows capacity

typedef __attribute__((ext_vector_type(4))) float  floatx4;
typedef __attribute__((ext_vector_type(8))) short  short8;

__device__ __forceinline__ unsigned short f2bf(float f) {
    union { float f; unsigned int u; } v; v.f = f;
    unsigned int u = v.u;
    unsigned int r = (u + 0x7FFFu + ((u >> 16) & 1u)) >> 16;  // RNE
    return (unsigned short)r;
}
__device__ __forceinline__ float bf2f(unsigned short h) {
    union { unsigned int u; float f; } v; v.u = ((unsigned int)h) << 16;
    return v.f;
}

// ---------------- router: one wave per token ----------------
__global__ __launch_bounds__(256) void router_kernel(
        const float* __restrict__ x, const float* __restrict__ wsw,
        const float* __restrict__ bsw, int* __restrict__ routes,
        int* __restrict__ cnt, float* __restrict__ rps) {
    __shared__ float srps[N_EXP];
    __shared__ int   scnt[N_EXP];
    int tid = threadIdx.x;
    if (tid < N_EXP) { srps[tid] = 0.f; scnt[tid] = 0; }
    __syncthreads();
    int wave = tid >> 6, l = tid & 63;
    int t = blockIdx.x * 4 + wave;
    const float* xr = x + (size_t)t * D_MODEL;
    double acc[N_EXP];
#pragma unroll
    for (int e = 0; e < N_EXP; e++) acc[e] = 0.0;
    for (int d = l; d < D_MODEL; d += 64) {
        float xv = xr[d];
        const float* wr = wsw + d * N_EXP;
#pragma unroll
        for (int e = 0; e < N_EXP; e++) acc[e] += (double)xv * (double)wr[e];
    }
#pragma unroll
    for (int off = 32; off > 0; off >>= 1) {
#pragma unroll
        for (int e = 0; e < N_EXP; e++) acc[e] += __shfl_xor(acc[e], off, 64);
    }
    if (l == 0) {
        float logit[N_EXP];
        float mx = -1e30f; int am = 0;
#pragma unroll
        for (int e = 0; e < N_EXP; e++) {
            logit[e] = (float)acc[e] + bsw[e];
            if (logit[e] > mx) { mx = logit[e]; am = e; }
        }
        float p[N_EXP]; float s = 0.f;
#pragma unroll
        for (int e = 0; e < N_EXP; e++) { p[e] = __expf(logit[e] - mx); s += p[e]; }
        float inv = 1.f / s;
        routes[t] = am;
        atomicAdd(&scnt[am], 1);
#pragma unroll
        for (int e = 0; e < N_EXP; e++) atomicAdd(&srps[e], p[e] * inv);
    }
    __syncthreads();
    if (tid < N_EXP) {
        atomicAdd(&cnt[tid], scnt[tid]);
        atomicAdd(&rps[tid], srps[tid]);
    }
}

// ---------------- plan: offsets, tile table, output tail ----------------
__global__ void plan_kernel(const int* __restrict__ cnt, const float* __restrict__ rps,
                            int* __restrict__ astart, int* __restrict__ cursor,
                            int* __restrict__ tile_e, int* __restrict__ tile_m0,
                            float* __restrict__ out_tail) {
    if (threadIdx.x == 0 && blockIdx.x == 0) {
        int a = 0, idx = 0;
        for (int e = 0; e < N_EXP; e++) {
            astart[e] = a; cursor[e] = a;
            int nt = (cnt[e] + BM - 1) / BM;
            for (int j = 0; j < nt; j++) { tile_e[idx] = e; tile_m0[idx] = a + j * BM; idx++; }
            a += nt * BM;
        }
        for (; idx < MAX_TILES; idx++) { tile_e[idx] = -1; tile_m0[idx] = 0; }
        for (int e = 0; e < N_EXP; e++) {
            out_tail[e] = (float)cnt[e];
            out_tail[N_EXP + e] = rps[e];
        }
        out_tail[2 * N_EXP] = 0.0f;   // n_dropped = 0
    }
}

// ---------------- fused scatter + gather/cast: one wave per token ----------------
__global__ __launch_bounds__(256) void scatter_gather_kernel(
        const float* __restrict__ x, const int* __restrict__ routes,
        int* __restrict__ cursor, int* __restrict__ perm, int* __restrict__ tinv,
        unsigned short* __restrict__ Xs) {
    int wave = threadIdx.x >> 6, l = threadIdx.x & 63;
    int t = blockIdx.x * 4 + wave;
    int pos = 0;
    if (l == 0) {
        int e = routes[t];
        pos = atomicAdd(&cursor[e], 1);
        perm[pos] = t;
        tinv[t] = pos;
    }
    pos = __shfl(pos, 0, 64);
    const float4* src = (const float4*)(x + (size_t)t * D_MODEL);
    ushort4* dst = (ushort4*)(Xs + (size_t)pos * D_MODEL);
#pragma unroll
    for (int i = 0; i < 3; i++) {
        float4 v = src[i * 64 + l];
        ushort4 o;
        o.x = f2bf(v.x); o.y = f2bf(v.y); o.z = f2bf(v.z); o.w = f2bf(v.w);
        dst[i * 64 + l] = o;
    }
}

// ---------------- transpose + cast fp32 [R][C] -> bf16 [C][R], per expert ----------------
__global__ __launch_bounds__(256) void transpose_cast_kernel(
        const float* __restrict__ src, unsigned short* __restrict__ dst, int R, int C) {
    __shared__ float tile[64][65];
    int e = blockIdx.z;
    const float* s = src + (size_t)e * R * C;
    unsigned short* d = dst + (size_t)e * R * C;
    int tx = threadIdx.x & 63;
    int ty = threadIdx.x >> 6;            // 0..3
    int c0 = blockIdx.x * 64, r0 = blockIdx.y * 64;
#pragma unroll
    for (int k = 0; k < 16; k++) {
        int r = ty + k * 4;
        tile[r][tx] = s[(size_t)(r0 + r) * C + (c0 + tx)];
    }
    __syncthreads();
#pragma unroll
    for (int k = 0; k < 16; k++) {
        int c = ty + k * 4;
        ushort2 v;
        v.x = f2bf(tile[tx * 2][c]);
        v.y = f2bf(tile[tx * 2 + 1][c]);
        *(ushort2*)(&d[(size_t)(c0 + c) * R + (r0 + tx * 2)]) = v;
    }
}

// ============ shared GEMM inner loop pieces (BK=64, XOR-swizzled LDS) ============
// LDS tile: 128 rows x 64 bf16 (128B rows = 8 chunks of 16B).
// Physical chunk p = logical chunk q ^ (row & 7)  -> conflict-free ds_read_b128.
// Staging: lane l of wave w covers row (w*8 + s*32 + (l>>3)), physical chunk (l&7),
// so it must FETCH global logical chunk (l&7) ^ (l>>3).

#define GLL(gaddr, laddr) \
    __builtin_amdgcn_global_load_lds((const __attribute__((address_space(1))) unsigned int*)(gaddr), \
                                     (__attribute__((address_space(3))) unsigned int*)(laddr), 16, 0, 0)

// ---------------- GEMM1: Y1 = relu(Xs * Wt1^T), 128x128x(BK=64) ----------------
// A: Xs [MCAP][768].  Bt: Wt [E][3072][768].  Out: Y1 [MCAP][3072] bf16.
__global__ __launch_bounds__(256) void gemm1_kernel(
        const unsigned short* __restrict__ A, const unsigned short* __restrict__ Bt,
        const int* __restrict__ tile_e, const int* __restrict__ tile_m0,
        unsigned short* __restrict__ Obf) {
    const int K = D_MODEL, N = F_FF;
    int e = tile_e[blockIdx.y];
    if (e < 0) return;
    int m0 = tile_m0[blockIdx.y];
    int n0 = blockIdx.x * 128;
    const unsigned short* Be = Bt + (size_t)e * N * K;

    __shared__ __align__(16) unsigned short ldsA[128 * 64];
    __shared__ __align__(16) unsigned short ldsB[128 * 64];

    int tid = threadIdx.x;
    int w = tid >> 6, l = tid & 63;
    int wm = w & 1, wn = w >> 1;
    int quad = l >> 4, l15 = l & 15;
    int s7 = l15 & 7;

    floatx4 zero = {0.f, 0.f, 0.f, 0.f};
    floatx4 acc[4][4];
#pragma unroll
    for (int i = 0; i < 4; i++)
#pragma unroll
        for (int j = 0; j < 4; j++) acc[i][j] = zero;

    int rl = l >> 3;                       // row within 8-row instr group
    int q  = (l & 7) ^ rl;                 // swizzled source chunk
    int r0 = w * 8 + rl;
    const char* gA = (const char*)(A + (size_t)(m0 + r0) * K) + q * 16;
    const char* gB = (const char*)(Be + (size_t)(n0 + r0) * K) + q * 16;
    char* lA = (char*)ldsA + w * 1024;
    char* lB = (char*)ldsB + w * 1024;
    const size_t rowskip = (size_t)32 * K * 2;   // +32 rows in bytes

#pragma unroll 1
    for (int kc = 0; kc < K; kc += 64) {
        const char* ga = gA + kc * 2;
        const char* gb = gB + kc * 2;
#pragma unroll
        for (int s = 0; s < 4; s++) {
            GLL(ga + s * rowskip, lA + s * 4096);
            GLL(gb + s * rowskip, lB + s * 4096);
        }
        __syncthreads();
#pragma unroll
        for (int kk = 0; kk < 2; kk++) {
            int p = (kk * 4 + quad) ^ s7;
            short8 af[4], bf[4];
#pragma unroll
            for (int i = 0; i < 4; i++)
                af[i] = *(const short8*)((const char*)ldsA + (wm * 64 + i * 16 + l15) * 128 + p * 16);
#pragma unroll
            for (int j = 0; j < 4; j++)
                bf[j] = *(const short8*)((const char*)ldsB + (wn * 64 + j * 16 + l15) * 128 + p * 16);
#pragma unroll
            for (int i = 0; i < 4; i++)
#pragma unroll
                for (int j = 0; j < 4; j++)
                    acc[i][j] = __builtin_amdgcn_mfma_f32_16x16x32_bf16(af[i], bf[j], acc[i][j], 0, 0, 0);
        }
        __syncthreads();
    }

#pragma unroll
    for (int i = 0; i < 4; i++) {
#pragma unroll
        for (int r = 0; r < 4; r++) {
            int row = m0 + wm * 64 + i * 16 + quad * 4 + r;
            size_t base = (size_t)row * N + n0 + wn * 64 + l15;
#pragma unroll
            for (int j = 0; j < 4; j++) {
                float v = acc[i][j][r];
                v = v > 0.f ? v : 0.f;
                Obf[base + j * 16] = f2bf(v);
            }
        }
    }
}

// ---------------- GEMM2: split-K=4, BK=64 ----------------
// A: Y1 [MCAP][3072].  Bt: Wt [E][768][3072].
// PARTIAL: store bf16 partials Pb[ks][MCAP][768]; else atomicAdd fp32 into out via perm.
template <bool PARTIAL>
__global__ __launch_bounds__(256) void gemm2_kernel(
        const unsigned short* __restrict__ A, const unsigned short* __restrict__ Bt,
        const int* __restrict__ tile_e, const int* __restrict__ tile_m0,
        const int* __restrict__ perm, unsigned short* __restrict__ Pb,
        float* __restrict__ Of32) {
    const int K = F_FF, N = D_MODEL, KQ = F_FF / 4;
    int bid = blockIdx.x;
    int m_idx = bid % MAX_TILES;
    int strip = bid / MAX_TILES;          // 0..23
    int e = tile_e[m_idx];
    if (e < 0) return;
    int m0 = tile_m0[m_idx];
    int ks = strip / 6;
    int n0 = (strip % 6) * 128;
    const unsigned short* Be = Bt + (size_t)e * N * K;

    __shared__ __align__(16) unsigned short ldsA[128 * 64];
    __shared__ __align__(16) unsigned short ldsB[128 * 64];

    int tid = threadIdx.x;
    int w = tid >> 6, l = tid & 63;
    int wm = w & 1, wn = w >> 1;
    int quad = l >> 4, l15 = l & 15;
    int s7 = l15 & 7;

    floatx4 zero = {0.f, 0.f, 0.f, 0.f};
    floatx4 acc[4][4];
#pragma unroll
    for (int i = 0; i < 4; i++)
#pragma unroll
        for (int j = 0; j < 4; j++) acc[i][j] = zero;

    int rl = l >> 3;
    int q  = (l & 7) ^ rl;
    int r0 = w * 8 + rl;
    const char* gA = (const char*)(A + (size_t)(m0 + r0) * K) + q * 16;
    const char* gB = (const char*)(Be + (size_t)(n0 + r0) * K) + q * 16;
    char* lA = (char*)ldsA + w * 1024;
    char* lB = (char*)ldsB + w * 1024;
    const size_t rowskip = (size_t)32 * K * 2;

    int k_lo = ks * KQ, k_hi = k_lo + KQ;
#pragma unroll 1
    for (int kc = k_lo; kc < k_hi; kc += 64) {
        const char* ga = gA + kc * 2;
        const char* gb = gB + kc * 2;
#pragma unroll
        for (int s = 0; s < 4; s++) {
            GLL(ga + s * rowskip, lA + s * 4096);
            GLL(gb + s * rowskip, lB + s * 4096);
        }
        __syncthreads();
#pragma unroll
        for (int kk = 0; kk < 2; kk++) {
            int p = (kk * 4 + quad) ^ s7;
            short8 af[4], bf[4];
#pragma unroll
            for (int i = 0; i < 4; i++)
                af[i] = *(const short8*)((const char*)ldsA + (wm * 64 + i * 16 + l15) * 128 + p * 16);
#pragma unroll
            for (int j = 0; j < 4; j++)
                bf[j] = *(const short8*)((const char*)ldsB + (wn * 64 + j * 16 + l15) * 128 + p * 16);
#pragma unroll
            for (int i = 0; i < 4; i++)
#pragma unroll
                for (int j = 0; j < 4; j++)
                    acc[i][j] = __builtin_amdgcn_mfma_f32_16x16x32_bf16(af[i], bf[j], acc[i][j], 0, 0, 0);
        }
        __syncthreads();
    }

    if (PARTIAL) {
#pragma unroll
        for (int i = 0; i < 4; i++) {
#pragma unroll
            for (int r = 0; r < 4; r++) {
                int row = m0 + wm * 64 + i * 16 + quad * 4 + r;
                size_t base = (size_t)(ks * MCAP + row) * N + n0 + wn * 64 + l15;
#pragma unroll
                for (int j = 0; j < 4; j++)
                    Pb[base + j * 16] = f2bf(acc[i][j][r]);
            }
        }
    } else {
#pragma unroll
        for (int i = 0; i < 4; i++) {
#pragma unroll
            for (int r = 0; r < 4; r++) {
                int row = m0 + wm * 64 + i * 16 + quad * 4 + r;
                int t = perm[row];
                if (t < 0) continue;
                size_t base = (size_t)t * N + n0 + wn * 64 + l15;
#pragma unroll
                for (int j = 0; j < 4; j++)
                    atomicAdd(&Of32[base + j * 16], acc[i][j][r]);
            }
        }
    }
}

// ---------------- reduce: out[t] = sum_ks Pb[ks][tinv[t]] ----------------
__global__ __launch_bounds__(256) void reduce_kernel(
        const unsigned short* __restrict__ Pb, const int* __restrict__ tinv,
        float* __restrict__ out) {
    int t = blockIdx.x;
    int m = tinv[t];
    const unsigned short* p0 = Pb + (size_t)m * D_MODEL;
    float* o = out + (size_t)t * D_MODEL;
#pragma unroll
    for (int it = 0; it < 3; it++) {
        int d = it * 256 + threadIdx.x;
        float s = 0.f;
#pragma unroll
        for (int ks = 0; ks < 4; ks++)
            s += bf2f(p0[(size_t)ks * MCAP * D_MODEL + d]);
        o[d] = s;
    }
}

extern "C" void kernel_launch(void* const* d_in, const int* in_sizes, int n_in,
                              void* d_out, int out_size, void* d_ws, size_t ws_size,
                              hipStream_t stream) {
    const float* x   = (const float*)d_in[0];
    const float* wsw = (const float*)d_in[1];
    const float* bsw = (const float*)d_in[2];
    const float* wi  = (const float*)d_in[3];
    const float* wo  = (const float*)d_in[4];
    float* out = (float*)d_out;

    char* ws = (char*)d_ws;
    int*   cnt     = (int*)(ws + 0);
    float* rps     = (float*)(ws + 64);
    int*   cursor  = (int*)(ws + 128);
    int*   astart  = (int*)(ws + 192);
    int*   tile_e  = (int*)(ws + 256);
    int*   tile_m0 = (int*)(ws + 512);
    int*   perm    = (int*)(ws + 1024);                   // MCAP ints  -> 21504
    int*   routes  = (int*)(ws + 21504);                  // 4096 ints  -> 37888
    int*   tinv    = (int*)(ws + 37888);                  // 4096 ints  -> 54272
    unsigned short* Xs = (unsigned short*)(ws + 54272);   // 7,864,320  -> 7,918,592
    unsigned short* Y1 = (unsigned short*)(ws + 7918592); // 31,457,280 -> 39,375,872
    unsigned short* Wt = (unsigned short*)(ws + 39375872);// 37,748,736 -> 77,124,608
    unsigned short* Pb = (unsigned short*)(ws + 77124608);// 31,457,280 -> 108,581,888
    const bool use_partial = ws_size >= 108581888ull;     // constant per process: graph-safe

    hipMemsetAsync(ws, 0, 1024, stream);
    hipMemsetAsync(ws + 1024, 0xFF, MCAP * 4, stream);    // perm = -1
    if (!use_partial)
        hipMemsetAsync(out, 0, (size_t)T_TOK * D_MODEL * 4, stream);

    router_kernel<<<T_TOK / 4, 256, 0, stream>>>(x, wsw, bsw, routes, cnt, rps);
    plan_kernel<<<1, 64, 0, stream>>>(cnt, rps, astart, cursor, tile_e, tile_m0,
                                      out + (size_t)T_TOK * D_MODEL);
    scatter_gather_kernel<<<T_TOK / 4, 256, 0, stream>>>(x, routes, cursor, perm, tinv, Xs);

    // wi [E][D][F] -> Wt [E][F][D]
    transpose_cast_kernel<<<dim3(F_FF / 64, D_MODEL / 64, N_EXP), 256, 0, stream>>>(wi, Wt, D_MODEL, F_FF);
    gemm1_kernel<<<dim3(F_FF / 128, MAX_TILES), 256, 0, stream>>>(Xs, Wt, tile_e, tile_m0, Y1);

    // wo [E][F][D] -> Wt [E][D][F]
    transpose_cast_kernel<<<dim3(D_MODEL / 64, F_FF / 64, N_EXP), 256, 0, stream>>>(wo, Wt, F_FF, D_MODEL);
    if (use_partial) {
        gemm2_kernel<true><<<24 * MAX_TILES, 256, 0, stream>>>(Y1, Wt, tile_e, tile_m0, perm, Pb, out);
        reduce_kernel<<<T_TOK, 256, 0, stream>>>(Pb, tinv, out);
    } else {
        gemm2_kernel<false><<<24 * MAX_TILES, 256, 0, stream>>>(Y1, Wt, tile_e, tile_m0, perm, Pb, out);
    }
}

// Round 4
// 307.847 us; speedup vs baseline: 1.2830x; 1.1677x over previous
//
#include <hip/hip_runtime.h>
#include <stdint.h>

#define T_TOK   4096
#define D_MODEL 768
#define F_FF    3072
#define N_EXP   8
#define BM      128
#define MAX_TILES 40
#define MCAP    (MAX_TILES * BM)   // 5120 padded rows capacity

typedef __attribute__((ext_vector_type(4))) float  floatx4;
typedef __attribute__((ext_vector_type(8))) short  short8;

__device__ __forceinline__ unsigned short f2bf(float f) {
    union { float f; unsigned int u; } v; v.f = f;
    unsigned int u = v.u;
    unsigned int r = (u + 0x7FFFu + ((u >> 16) & 1u)) >> 16;  // RNE
    return (unsigned short)r;
}
__device__ __forceinline__ float bf2f(unsigned short h) {
    union { unsigned int u; float f; } v; v.u = ((unsigned int)h) << 16;
    return v.f;
}

// ---------------- router: one wave per token; per-block partials, NO global atomics ----------------
__global__ __launch_bounds__(256) void router_kernel(
        const float* __restrict__ x, const float* __restrict__ wsw,
        const float* __restrict__ bsw, int* __restrict__ routes,
        int* __restrict__ cnt_part, float* __restrict__ rps_part) {
    __shared__ float srps[N_EXP];
    __shared__ int   scnt[N_EXP];
    int tid = threadIdx.x;
    if (tid < N_EXP) { srps[tid] = 0.f; scnt[tid] = 0; }
    __syncthreads();
    int wave = tid >> 6, l = tid & 63;
    int t = blockIdx.x * 4 + wave;
    const float* xr = x + (size_t)t * D_MODEL;
    double acc[N_EXP];
#pragma unroll
    for (int e = 0; e < N_EXP; e++) acc[e] = 0.0;
    for (int d = l; d < D_MODEL; d += 64) {
        float xv = xr[d];
        const float* wr = wsw + d * N_EXP;
#pragma unroll
        for (int e = 0; e < N_EXP; e++) acc[e] += (double)xv * (double)wr[e];
    }
#pragma unroll
    for (int off = 32; off > 0; off >>= 1) {
#pragma unroll
        for (int e = 0; e < N_EXP; e++) acc[e] += __shfl_xor(acc[e], off, 64);
    }
    if (l == 0) {
        float logit[N_EXP];
        float mx = -1e30f; int am = 0;
#pragma unroll
        for (int e = 0; e < N_EXP; e++) {
            logit[e] = (float)acc[e] + bsw[e];
            if (logit[e] > mx) { mx = logit[e]; am = e; }
        }
        float p[N_EXP]; float s = 0.f;
#pragma unroll
        for (int e = 0; e < N_EXP; e++) { p[e] = __expf(logit[e] - mx); s += p[e]; }
        float inv = 1.f / s;
        routes[t] = am;
        atomicAdd(&scnt[am], 1);                     // LDS atomics only
#pragma unroll
        for (int e = 0; e < N_EXP; e++) atomicAdd(&srps[e], p[e] * inv);
    }
    __syncthreads();
    if (tid < N_EXP) {
        cnt_part[blockIdx.x * N_EXP + tid] = scnt[tid];
        rps_part[blockIdx.x * N_EXP + tid] = srps[tid];
    }
}

// ---------------- plan: reduce partials, build offsets/tiles/out-tail ----------------
__global__ __launch_bounds__(256) void plan_kernel(
        const int* __restrict__ cnt_part, const float* __restrict__ rps_part,
        int* __restrict__ cnt, float* __restrict__ rps,
        int* __restrict__ astart, int* __restrict__ cursor,
        int* __restrict__ tile_e, int* __restrict__ tile_m0,
        float* __restrict__ out_tail) {
    __shared__ int   sc[N_EXP][32];
    __shared__ float sp[N_EXP][32];
    int tid = threadIdx.x;
    int e = tid & 7, chunk = tid >> 3;                 // 32 chunks x 32 blocks
    int ci = 0; float pf = 0.f;
#pragma unroll 4
    for (int b = chunk * 32; b < chunk * 32 + 32; b++) {
        ci += cnt_part[b * N_EXP + e];
        pf += rps_part[b * N_EXP + e];
    }
    sc[e][chunk] = ci; sp[e][chunk] = pf;
    __syncthreads();
    if (tid < N_EXP) {
        int s = 0; float f = 0.f;
        for (int c2 = 0; c2 < 32; c2++) { s += sc[tid][c2]; f += sp[tid][c2]; }
        cnt[tid] = s; rps[tid] = f;
        out_tail[tid] = (float)s;
        out_tail[N_EXP + tid] = f;
    }
    __syncthreads();
    if (tid == 0) {
        out_tail[2 * N_EXP] = 0.0f;                    // n_dropped
        int a = 0, idx = 0;
        for (int e2 = 0; e2 < N_EXP; e2++) {
            astart[e2] = a; cursor[e2] = a;
            int nt = (cnt[e2] + BM - 1) / BM;
            for (int j = 0; j < nt; j++) { tile_e[idx] = e2; tile_m0[idx] = a + j * BM; idx++; }
            a += nt * BM;
        }
        for (; idx < MAX_TILES; idx++) { tile_e[idx] = -1; tile_m0[idx] = 0; }
    }
}

// ---------------- assign: block-aggregated positions (128 global atomics total) ----------------
__global__ __launch_bounds__(256) void assign_kernel(
        const int* __restrict__ routes, int* __restrict__ cursor,
        int* __restrict__ perm, int* __restrict__ tinv) {
    __shared__ int lcnt[N_EXP], sbase[N_EXP];
    int tid = threadIdx.x;
    if (tid < N_EXP) lcnt[tid] = 0;
    __syncthreads();
    int t = blockIdx.x * 256 + tid;
    int e = routes[t];
    int rank = atomicAdd(&lcnt[e], 1);                 // LDS atomic
    __syncthreads();
    if (tid < N_EXP) sbase[tid] = atomicAdd(&cursor[tid], lcnt[tid]);
    __syncthreads();
    int pos = sbase[e] + rank;
    perm[pos] = t;
    tinv[t] = pos;
}

// ---------------- gather/cast: pure copy, one wave per token ----------------
__global__ __launch_bounds__(256) void gather_kernel(
        const float* __restrict__ x, const int* __restrict__ tinv,
        unsigned short* __restrict__ Xs) {
    int wave = threadIdx.x >> 6, l = threadIdx.x & 63;
    int t = blockIdx.x * 4 + wave;
    int pos = tinv[t];
    const float4* src = (const float4*)(x + (size_t)t * D_MODEL);
    ushort4* dst = (ushort4*)(Xs + (size_t)pos * D_MODEL);
#pragma unroll
    for (int i = 0; i < 3; i++) {
        float4 v = src[i * 64 + l];
        ushort4 o;
        o.x = f2bf(v.x); o.y = f2bf(v.y); o.z = f2bf(v.z); o.w = f2bf(v.w);
        dst[i * 64 + l] = o;
    }
}

// ---------------- transpose + cast fp32 [R][C] -> bf16 [C][R], per expert ----------------
// phase1: coalesced row reads -> LDS (2-way, free). phase2: ushort4 (8B/lane) writes;
// LDS read banks (4*rg + i + c) % 32 -> each bank exactly 2 lanes (free).
__global__ __launch_bounds__(256) void transpose_cast_kernel(
        const float* __restrict__ src, unsigned short* __restrict__ dst, int R, int C) {
    __shared__ float tile[64][65];
    int e = blockIdx.z;
    const float* s = src + (size_t)e * R * C;
    unsigned short* d = dst + (size_t)e * R * C;
    int tx = threadIdx.x & 63;
    int ty = threadIdx.x >> 6;            // 0..3
    int c0 = blockIdx.x * 64, r0 = blockIdx.y * 64;
#pragma unroll
    for (int k = 0; k < 16; k++) {
        int r = ty * 16 + k;
        tile[r][tx] = s[(size_t)(r0 + r) * C + (c0 + tx)];
    }
    __syncthreads();
    int rg = threadIdx.x & 15;            // rows 4rg..4rg+3
    int ch = threadIdx.x >> 4;            // 0..15
#pragma unroll
    for (int k = 0; k < 4; k++) {
        int c = ch + 16 * k;
        ushort4 v;
        v.x = f2bf(tile[4 * rg + 0][c]);
        v.y = f2bf(tile[4 * rg + 1][c]);
        v.z = f2bf(tile[4 * rg + 2][c]);
        v.w = f2bf(tile[4 * rg + 3][c]);
        *(ushort4*)(&d[(size_t)(c0 + c) * R + (r0 + 4 * rg)]) = v;
    }
}

// ============ GEMM core (BK=64, XOR-swizzled LDS) ============
#define GLL(gaddr, laddr) \
    __builtin_amdgcn_global_load_lds((const __attribute__((address_space(1))) unsigned int*)(gaddr), \
                                     (__attribute__((address_space(3))) unsigned int*)(laddr), 16, 0, 0)

// ---------------- GEMM1: Y1 = relu(Xs * Wt1^T), 128x128x(BK=64) ----------------
__global__ __launch_bounds__(256) void gemm1_kernel(
        const unsigned short* __restrict__ A, const unsigned short* __restrict__ Bt,
        const int* __restrict__ tile_e, const int* __restrict__ tile_m0,
        unsigned short* __restrict__ Obf) {
    const int K = D_MODEL, N = F_FF;
    int e = tile_e[blockIdx.y];
    if (e < 0) return;
    int m0 = tile_m0[blockIdx.y];
    int n0 = blockIdx.x * 128;
    const unsigned short* Be = Bt + (size_t)e * N * K;

    __shared__ __align__(16) unsigned short ldsA[128 * 64];
    __shared__ __align__(16) unsigned short ldsB[128 * 64];

    int tid = threadIdx.x;
    int w = tid >> 6, l = tid & 63;
    int wm = w & 1, wn = w >> 1;
    int quad = l >> 4, l15 = l & 15;
    int s7 = l15 & 7;

    floatx4 zero = {0.f, 0.f, 0.f, 0.f};
    floatx4 acc[4][4];
#pragma unroll
    for (int i = 0; i < 4; i++)
#pragma unroll
        for (int j = 0; j < 4; j++) acc[i][j] = zero;

    int rl = l >> 3;
    int q  = (l & 7) ^ rl;
    int r0 = w * 8 + rl;
    const char* gA = (const char*)(A + (size_t)(m0 + r0) * K) + q * 16;
    const char* gB = (const char*)(Be + (size_t)(n0 + r0) * K) + q * 16;
    char* lA = (char*)ldsA + w * 1024;
    char* lB = (char*)ldsB + w * 1024;
    const size_t rowskip = (size_t)32 * K * 2;

#pragma unroll 1
    for (int kc = 0; kc < K; kc += 64) {
        const char* ga = gA + kc * 2;
        const char* gb = gB + kc * 2;
#pragma unroll
        for (int s = 0; s < 4; s++) {
            GLL(ga + s * rowskip, lA + s * 4096);
            GLL(gb + s * rowskip, lB + s * 4096);
        }
        __syncthreads();
#pragma unroll
        for (int kk = 0; kk < 2; kk++) {
            int p = (kk * 4 + quad) ^ s7;
            short8 af[4], bf[4];
#pragma unroll
            for (int i = 0; i < 4; i++)
                af[i] = *(const short8*)((const char*)ldsA + (wm * 64 + i * 16 + l15) * 128 + p * 16);
#pragma unroll
            for (int j = 0; j < 4; j++)
                bf[j] = *(const short8*)((const char*)ldsB + (wn * 64 + j * 16 + l15) * 128 + p * 16);
#pragma unroll
            for (int i = 0; i < 4; i++)
#pragma unroll
                for (int j = 0; j < 4; j++)
                    acc[i][j] = __builtin_amdgcn_mfma_f32_16x16x32_bf16(af[i], bf[j], acc[i][j], 0, 0, 0);
        }
        __syncthreads();
    }

#pragma unroll
    for (int i = 0; i < 4; i++) {
#pragma unroll
        for (int r = 0; r < 4; r++) {
            int row = m0 + wm * 64 + i * 16 + quad * 4 + r;
            size_t base = (size_t)row * N + n0 + wn * 64 + l15;
#pragma unroll
            for (int j = 0; j < 4; j++) {
                float v = acc[i][j][r];
                v = v > 0.f ? v : 0.f;
                Obf[base + j * 16] = f2bf(v);
            }
        }
    }
}

// ---------------- GEMM2: split-K=4, BK=64 ----------------
template <bool PARTIAL>
__global__ __launch_bounds__(256) void gemm2_kernel(
        const unsigned short* __restrict__ A, const unsigned short* __restrict__ Bt,
        const int* __restrict__ tile_e, const int* __restrict__ tile_m0,
        const int* __restrict__ perm, unsigned short* __restrict__ Pb,
        float* __restrict__ Of32) {
    const int K = F_FF, N = D_MODEL, KQ = F_FF / 4;
    int bid = blockIdx.x;
    int m_idx = bid % MAX_TILES;
    int strip = bid / MAX_TILES;          // 0..23
    int e = tile_e[m_idx];
    if (e < 0) return;
    int m0 = tile_m0[m_idx];
    int ks = strip / 6;
    int n0 = (strip % 6) * 128;
    const unsigned short* Be = Bt + (size_t)e * N * K;

    __shared__ __align__(16) unsigned short ldsA[128 * 64];
    __shared__ __align__(16) unsigned short ldsB[128 * 64];

    int tid = threadIdx.x;
    int w = tid >> 6, l = tid & 63;
    int wm = w & 1, wn = w >> 1;
    int quad = l >> 4, l15 = l & 15;
    int s7 = l15 & 7;

    floatx4 zero = {0.f, 0.f, 0.f, 0.f};
    floatx4 acc[4][4];
#pragma unroll
    for (int i = 0; i < 4; i++)
#pragma unroll
        for (int j = 0; j < 4; j++) acc[i][j] = zero;

    int rl = l >> 3;
    int q  = (l & 7) ^ rl;
    int r0 = w * 8 + rl;
    const char* gA = (const char*)(A + (size_t)(m0 + r0) * K) + q * 16;
    const char* gB = (const char*)(Be + (size_t)(n0 + r0) * K) + q * 16;
    char* lA = (char*)ldsA + w * 1024;
    char* lB = (char*)ldsB + w * 1024;
    const size_t rowskip = (size_t)32 * K * 2;

    int k_lo = ks * KQ, k_hi = k_lo + KQ;
#pragma unroll 1
    for (int kc = k_lo; kc < k_hi; kc += 64) {
        const char* ga = gA + kc * 2;
        const char* gb = gB + kc * 2;
#pragma unroll
        for (int s = 0; s < 4; s++) {
            GLL(ga + s * rowskip, lA + s * 4096);
            GLL(gb + s * rowskip, lB + s * 4096);
        }
        __syncthreads();
#pragma unroll
        for (int kk = 0; kk < 2; kk++) {
            int p = (kk * 4 + quad) ^ s7;
            short8 af[4], bf[4];
#pragma unroll
            for (int i = 0; i < 4; i++)
                af[i] = *(const short8*)((const char*)ldsA + (wm * 64 + i * 16 + l15) * 128 + p * 16);
#pragma unroll
            for (int j = 0; j < 4; j++)
                bf[j] = *(const short8*)((const char*)ldsB + (wn * 64 + j * 16 + l15) * 128 + p * 16);
#pragma unroll
            for (int i = 0; i < 4; i++)
#pragma unroll
                for (int j = 0; j < 4; j++)
                    acc[i][j] = __builtin_amdgcn_mfma_f32_16x16x32_bf16(af[i], bf[j], acc[i][j], 0, 0, 0);
        }
        __syncthreads();
    }

    if (PARTIAL) {
#pragma unroll
        for (int i = 0; i < 4; i++) {
#pragma unroll
            for (int r = 0; r < 4; r++) {
                int row = m0 + wm * 64 + i * 16 + quad * 4 + r;
                size_t base = (size_t)(ks * MCAP + row) * N + n0 + wn * 64 + l15;
#pragma unroll
                for (int j = 0; j < 4; j++)
                    Pb[base + j * 16] = f2bf(acc[i][j][r]);
            }
        }
    } else {
#pragma unroll
        for (int i = 0; i < 4; i++) {
#pragma unroll
            for (int r = 0; r < 4; r++) {
                int row = m0 + wm * 64 + i * 16 + quad * 4 + r;
                int t = perm[row];
                if (t < 0) continue;
                size_t base = (size_t)t * N + n0 + wn * 64 + l15;
#pragma unroll
                for (int j = 0; j < 4; j++)
                    atomicAdd(&Of32[base + j * 16], acc[i][j][r]);
            }
        }
    }
}

// ---------------- reduce: out[t] = sum_ks Pb[ks][tinv[t]] ----------------
__global__ __launch_bounds__(256) void reduce_kernel(
        const unsigned short* __restrict__ Pb, const int* __restrict__ tinv,
        float* __restrict__ out) {
    int t = blockIdx.x;
    int m = tinv[t];
    const unsigned short* p0 = Pb + (size_t)m * D_MODEL;
    float* o = out + (size_t)t * D_MODEL;
#pragma unroll
    for (int it = 0; it < 3; it++) {
        int d = it * 256 + threadIdx.x;
        float s = 0.f;
#pragma unroll
        for (int ks = 0; ks < 4; ks++)
            s += bf2f(p0[(size_t)ks * MCAP * D_MODEL + d]);
        o[d] = s;
    }
}

extern "C" void kernel_launch(void* const* d_in, const int* in_sizes, int n_in,
                              void* d_out, int out_size, void* d_ws, size_t ws_size,
                              hipStream_t stream) {
    const float* x   = (const float*)d_in[0];
    const float* wsw = (const float*)d_in[1];
    const float* bsw = (const float*)d_in[2];
    const float* wi  = (const float*)d_in[3];
    const float* wo  = (const float*)d_in[4];
    float* out = (float*)d_out;

    char* ws = (char*)d_ws;
    int*   cnt      = (int*)(ws + 0);
    float* rps      = (float*)(ws + 32);
    int*   cursor   = (int*)(ws + 64);
    int*   astart   = (int*)(ws + 96);
    int*   tile_e   = (int*)(ws + 128);                  // 40 ints -> 288
    int*   tile_m0  = (int*)(ws + 288);                  // 40 ints -> 448
    int*   perm     = (int*)(ws + 512);                  // 20480  -> 20992
    int*   routes   = (int*)(ws + 20992);                // 16384  -> 37376
    int*   tinv     = (int*)(ws + 37376);                // 16384  -> 53760
    int*   cnt_part = (int*)(ws + 53760);                // 32768  -> 86528
    float* rps_part = (float*)(ws + 86528);              // 32768  -> 119296
    unsigned short* Xs = (unsigned short*)(ws + 119808); // 7,864,320  -> 7,984,128
    unsigned short* Y1 = (unsigned short*)(ws + 7984128);// 31,457,280 -> 39,441,408
    unsigned short* Wt = (unsigned short*)(ws + 39441408);// 37,748,736 -> 77,190,144
    unsigned short* Pb = (unsigned short*)(ws + 77190144);// 31,457,280 -> 108,647,424
    const bool use_partial = ws_size >= 108647424ull;    // constant per process: graph-safe

    hipMemsetAsync(ws + 512, 0xFF, MCAP * 4, stream);    // perm = -1 (atomic-path safety)
    if (!use_partial)
        hipMemsetAsync(out, 0, (size_t)T_TOK * D_MODEL * 4, stream);

    router_kernel<<<T_TOK / 4, 256, 0, stream>>>(x, wsw, bsw, routes, cnt_part, rps_part);
    plan_kernel<<<1, 256, 0, stream>>>(cnt_part, rps_part, cnt, rps, astart, cursor,
                                       tile_e, tile_m0, out + (size_t)T_TOK * D_MODEL);
    assign_kernel<<<T_TOK / 256, 256, 0, stream>>>(routes, cursor, perm, tinv);
    gather_kernel<<<T_TOK / 4, 256, 0, stream>>>(x, tinv, Xs);

    // wi [E][D][F] -> Wt [E][F][D]
    transpose_cast_kernel<<<dim3(F_FF / 64, D_MODEL / 64, N_EXP), 256, 0, stream>>>(wi, Wt, D_MODEL, F_FF);
    gemm1_kernel<<<dim3(F_FF / 128, MAX_TILES), 256, 0, stream>>>(Xs, Wt, tile_e, tile_m0, Y1);

    // wo [E][F][D] -> Wt [E][D][F]
    transpose_cast_kernel<<<dim3(D_MODEL / 64, F_FF / 64, N_EXP), 256, 0, stream>>>(wo, Wt, F_FF, D_MODEL);
    if (use_partial) {
        gemm2_kernel<true><<<24 * MAX_TILES, 256, 0, stream>>>(Y1, Wt, tile_e, tile_m0, perm, Pb, out);
        reduce_kernel<<<T_TOK, 256, 0, stream>>>(Pb, tinv, out);
    } else {
        gemm2_kernel<false><<<24 * MAX_TILES, 256, 0, stream>>>(Y1, Wt, tile_e, tile_m0, perm, Pb, out);
    }
}

// Round 5
// 297.848 us; speedup vs baseline: 1.3261x; 1.0336x over previous
//
#include <hip/hip_runtime.h>
#include <stdint.h>

#define T_TOK   4096
#define D_MODEL 768
#define F_FF    3072
#define N_EXP   8
#define BM      128
#define MAX_TILES 40
#define MCAP    (MAX_TILES * BM)   // 5120 padded rows capacity

typedef __attribute__((ext_vector_type(4))) float  floatx4;
typedef __attribute__((ext_vector_type(8))) short  short8;

__device__ __forceinline__ unsigned short f2bf(float f) {
    union { float f; unsigned int u; } v; v.f = f;
    unsigned int u = v.u;
    unsigned int r = (u + 0x7FFFu + ((u >> 16) & 1u)) >> 16;  // RNE
    return (unsigned short)r;
}
__device__ __forceinline__ float bf2f(unsigned short h) {
    union { unsigned int u; float f; } v; v.u = ((unsigned int)h) << 16;
    return v.f;
}

// ---------------- router: one wave per token; per-block partials, NO global atomics ----------------
__global__ __launch_bounds__(256) void router_kernel(
        const float* __restrict__ x, const float* __restrict__ wsw,
        const float* __restrict__ bsw, int* __restrict__ routes,
        int* __restrict__ cnt_part, float* __restrict__ rps_part) {
    __shared__ float srps[N_EXP];
    __shared__ int   scnt[N_EXP];
    int tid = threadIdx.x;
    if (tid < N_EXP) { srps[tid] = 0.f; scnt[tid] = 0; }
    __syncthreads();
    int wave = tid >> 6, l = tid & 63;
    int t = blockIdx.x * 4 + wave;
    const float* xr = x + (size_t)t * D_MODEL;
    double acc[N_EXP];
#pragma unroll
    for (int e = 0; e < N_EXP; e++) acc[e] = 0.0;
    for (int d = l; d < D_MODEL; d += 64) {
        float xv = xr[d];
        const float* wr = wsw + d * N_EXP;
#pragma unroll
        for (int e = 0; e < N_EXP; e++) acc[e] += (double)xv * (double)wr[e];
    }
#pragma unroll
    for (int off = 32; off > 0; off >>= 1) {
#pragma unroll
        for (int e = 0; e < N_EXP; e++) acc[e] += __shfl_xor(acc[e], off, 64);
    }
    if (l == 0) {
        float logit[N_EXP];
        float mx = -1e30f; int am = 0;
#pragma unroll
        for (int e = 0; e < N_EXP; e++) {
            logit[e] = (float)acc[e] + bsw[e];
            if (logit[e] > mx) { mx = logit[e]; am = e; }
        }
        float p[N_EXP]; float s = 0.f;
#pragma unroll
        for (int e = 0; e < N_EXP; e++) { p[e] = __expf(logit[e] - mx); s += p[e]; }
        float inv = 1.f / s;
        routes[t] = am;
        atomicAdd(&scnt[am], 1);                     // LDS atomics only
#pragma unroll
        for (int e = 0; e < N_EXP; e++) atomicAdd(&srps[e], p[e] * inv);
    }
    __syncthreads();
    if (tid < N_EXP) {
        cnt_part[blockIdx.x * N_EXP + tid] = scnt[tid];
        rps_part[blockIdx.x * N_EXP + tid] = srps[tid];
    }
}

// ---------------- plan: reduce partials, build offsets/tiles/out-tail ----------------
__global__ __launch_bounds__(256) void plan_kernel(
        const int* __restrict__ cnt_part, const float* __restrict__ rps_part,
        int* __restrict__ cnt, float* __restrict__ rps,
        int* __restrict__ astart, int* __restrict__ cursor,
        int* __restrict__ tile_e, int* __restrict__ tile_m0,
        float* __restrict__ out_tail) {
    __shared__ int   sc[N_EXP][32];
    __shared__ float sp[N_EXP][32];
    int tid = threadIdx.x;
    int e = tid & 7, chunk = tid >> 3;                 // 32 chunks x 32 blocks
    int ci = 0; float pf = 0.f;
#pragma unroll 4
    for (int b = chunk * 32; b < chunk * 32 + 32; b++) {
        ci += cnt_part[b * N_EXP + e];
        pf += rps_part[b * N_EXP + e];
    }
    sc[e][chunk] = ci; sp[e][chunk] = pf;
    __syncthreads();
    if (tid < N_EXP) {
        int s = 0; float f = 0.f;
        for (int c2 = 0; c2 < 32; c2++) { s += sc[tid][c2]; f += sp[tid][c2]; }
        cnt[tid] = s; rps[tid] = f;
        out_tail[tid] = (float)s;
        out_tail[N_EXP + tid] = f;
    }
    __syncthreads();
    if (tid == 0) {
        out_tail[2 * N_EXP] = 0.0f;                    // n_dropped
        int a = 0, idx = 0;
        for (int e2 = 0; e2 < N_EXP; e2++) {
            astart[e2] = a; cursor[e2] = a;
            int nt = (cnt[e2] + BM - 1) / BM;
            for (int j = 0; j < nt; j++) { tile_e[idx] = e2; tile_m0[idx] = a + j * BM; idx++; }
            a += nt * BM;
        }
        for (; idx < MAX_TILES; idx++) { tile_e[idx] = -1; tile_m0[idx] = 0; }
    }
}

// ---------------- assign: block-aggregated positions (128 global atomics total) ----------------
__global__ __launch_bounds__(256) void assign_kernel(
        const int* __restrict__ routes, int* __restrict__ cursor,
        int* __restrict__ perm, int* __restrict__ tinv) {
    __shared__ int lcnt[N_EXP], sbase[N_EXP];
    int tid = threadIdx.x;
    if (tid < N_EXP) lcnt[tid] = 0;
    __syncthreads();
    int t = blockIdx.x * 256 + tid;
    int e = routes[t];
    int rank = atomicAdd(&lcnt[e], 1);                 // LDS atomic
    __syncthreads();
    if (tid < N_EXP) sbase[tid] = atomicAdd(&cursor[tid], lcnt[tid]);
    __syncthreads();
    int pos = sbase[e] + rank;
    perm[pos] = t;
    tinv[t] = pos;
}

// ---------------- gather/cast: pure copy, one wave per token ----------------
__global__ __launch_bounds__(256) void gather_kernel(
        const float* __restrict__ x, const int* __restrict__ tinv,
        unsigned short* __restrict__ Xs) {
    int wave = threadIdx.x >> 6, l = threadIdx.x & 63;
    int t = blockIdx.x * 4 + wave;
    int pos = tinv[t];
    const float4* src = (const float4*)(x + (size_t)t * D_MODEL);
    ushort4* dst = (ushort4*)(Xs + (size_t)pos * D_MODEL);
#pragma unroll
    for (int i = 0; i < 3; i++) {
        float4 v = src[i * 64 + l];
        ushort4 o;
        o.x = f2bf(v.x); o.y = f2bf(v.y); o.z = f2bf(v.z); o.w = f2bf(v.w);
        dst[i * 64 + l] = o;
    }
}

// ---------------- merged transpose+cast: wi [D][F]->W1 [F][D], wo [F][D]->W2 [D][F] ----------------
// z<8: wi expert z.  z>=8: wo expert z-8 (block coords swapped).
// phase1: float4 global reads -> LDS [64][68] (16B rows alignment, ~2-way banks).
// phase2: ushort4 writes, coalesced.
__global__ __launch_bounds__(256) void transpose_cast_kernel(
        const float* __restrict__ wi, const float* __restrict__ wo,
        unsigned short* __restrict__ W1, unsigned short* __restrict__ W2, int zoff) {
    __shared__ float tile[64][68];
    int z = blockIdx.z + zoff;
    const float* s; unsigned short* d; int R, C, bx, by;
    if (z < 8) {
        s = wi + (size_t)z * D_MODEL * F_FF; d = W1 + (size_t)z * D_MODEL * F_FF;
        R = D_MODEL; C = F_FF; bx = blockIdx.x; by = blockIdx.y;
    } else {
        int e = z - 8;
        s = wo + (size_t)e * F_FF * D_MODEL; d = W2 + (size_t)e * F_FF * D_MODEL;
        R = F_FF; C = D_MODEL; bx = blockIdx.y; by = blockIdx.x;
    }
    int c0 = bx * 64, r0 = by * 64;
    int rr = threadIdx.x >> 4, cg = threadIdx.x & 15;
#pragma unroll
    for (int k = 0; k < 4; k++) {
        int r = rr + k * 16;
        float4 v = *(const float4*)(s + (size_t)(r0 + r) * C + c0 + cg * 4);
        tile[r][cg * 4 + 0] = v.x; tile[r][cg * 4 + 1] = v.y;
        tile[r][cg * 4 + 2] = v.z; tile[r][cg * 4 + 3] = v.w;
    }
    __syncthreads();
    int rg = threadIdx.x & 15, ch = threadIdx.x >> 4;
#pragma unroll
    for (int k = 0; k < 4; k++) {
        int c = ch + 16 * k;
        ushort4 v;
        v.x = f2bf(tile[4 * rg + 0][c]);
        v.y = f2bf(tile[4 * rg + 1][c]);
        v.z = f2bf(tile[4 * rg + 2][c]);
        v.w = f2bf(tile[4 * rg + 3][c]);
        *(ushort4*)(&d[(size_t)(c0 + c) * R + (r0 + 4 * rg)]) = v;
    }
}

// ============ GEMM core: BK=128 (6 iters), XOR-16 swizzled LDS, 64 KB ============
// LDS tile 128 rows x 128 bf16 (256B rows = 16 chunks of 16B).
// phys chunk = logical ^ (row & 15). Staging: lane l of instr s, wave w:
// row = w*4 + s*16 + (l>>4), phys = l&15, so fetch logical (l&15)^((w*4+(l>>4))&15).
#define GLL(gaddr, laddr) \
    __builtin_amdgcn_global_load_lds((const __attribute__((address_space(1))) unsigned int*)(gaddr), \
                                     (__attribute__((address_space(3))) unsigned int*)(laddr), 16, 0, 0)

// ---------------- GEMM1: Y1 = relu(Xs * W1^T), 128x128x(BK=128) ----------------
__global__ __launch_bounds__(256) void gemm1_kernel(
        const unsigned short* __restrict__ A, const unsigned short* __restrict__ Bt,
        const int* __restrict__ tile_e, const int* __restrict__ tile_m0,
        unsigned short* __restrict__ Obf) {
    const int K = D_MODEL, N = F_FF;
    int e = tile_e[blockIdx.y];
    if (e < 0) return;
    int m0 = tile_m0[blockIdx.y];
    int n0 = blockIdx.x * 128;
    const unsigned short* Be = Bt + (size_t)e * N * K;

    __shared__ __align__(16) unsigned short ldsA[128 * 128];
    __shared__ __align__(16) unsigned short ldsB[128 * 128];

    int tid = threadIdx.x;
    int w = tid >> 6, l = tid & 63;
    int wm = w & 1, wn = w >> 1;
    int quad = l >> 4, l15 = l & 15;

    floatx4 zero = {0.f, 0.f, 0.f, 0.f};
    floatx4 acc[4][4];
#pragma unroll
    for (int i = 0; i < 4; i++)
#pragma unroll
        for (int j = 0; j < 4; j++) acc[i][j] = zero;

    int rl = l >> 4;                               // 0..3
    int q  = (l & 15) ^ ((w * 4 + rl) & 15);       // swizzled source chunk
    int r0 = w * 4 + rl;
    const char* gA = (const char*)(A + (size_t)(m0 + r0) * K) + q * 16;
    const char* gB = (const char*)(Be + (size_t)(n0 + r0) * K) + q * 16;
    char* lA = (char*)ldsA + w * 1024;
    char* lB = (char*)ldsB + w * 1024;
    const size_t rowskip = (size_t)16 * K * 2;     // +16 rows, bytes

#pragma unroll 1
    for (int kc = 0; kc < K; kc += 128) {
        const char* ga = gA + kc * 2;
        const char* gb = gB + kc * 2;
#pragma unroll
        for (int s = 0; s < 8; s++) {
            GLL(ga + s * rowskip, lA + s * 4096);
            GLL(gb + s * rowskip, lB + s * 4096);
        }
        __syncthreads();
#pragma unroll
        for (int kk = 0; kk < 4; kk++) {
            int p = (kk * 4 + quad) ^ l15;
            short8 af[4], bf[4];
#pragma unroll
            for (int i = 0; i < 4; i++)
                af[i] = *(const short8*)((const char*)ldsA + (wm * 64 + i * 16 + l15) * 256 + p * 16);
#pragma unroll
            for (int j = 0; j < 4; j++)
                bf[j] = *(const short8*)((const char*)ldsB + (wn * 64 + j * 16 + l15) * 256 + p * 16);
#pragma unroll
            for (int i = 0; i < 4; i++)
#pragma unroll
                for (int j = 0; j < 4; j++)
                    acc[i][j] = __builtin_amdgcn_mfma_f32_16x16x32_bf16(af[i], bf[j], acc[i][j], 0, 0, 0);
        }
        __syncthreads();
    }

#pragma unroll
    for (int i = 0; i < 4; i++) {
#pragma unroll
        for (int r = 0; r < 4; r++) {
            int row = m0 + wm * 64 + i * 16 + quad * 4 + r;
            size_t base = (size_t)row * N + n0 + wn * 64 + l15;
#pragma unroll
            for (int j = 0; j < 4; j++) {
                float v = acc[i][j][r];
                v = v > 0.f ? v : 0.f;
                Obf[base + j * 16] = f2bf(v);
            }
        }
    }
}

// ---------------- GEMM2: split-K=4, BK=128 ----------------
template <bool PARTIAL>
__global__ __launch_bounds__(256) void gemm2_kernel(
        const unsigned short* __restrict__ A, const unsigned short* __restrict__ Bt,
        const int* __restrict__ tile_e, const int* __restrict__ tile_m0,
        const int* __restrict__ perm, unsigned short* __restrict__ Pb,
        float* __restrict__ Of32) {
    const int K = F_FF, N = D_MODEL, KQ = F_FF / 4;
    int bid = blockIdx.x;
    int m_idx = bid % MAX_TILES;
    int strip = bid / MAX_TILES;          // 0..23; same-strip blocks 40 apart -> same XCD
    int e = tile_e[m_idx];
    if (e < 0) return;
    int m0 = tile_m0[m_idx];
    int ks = strip / 6;
    int n0 = (strip % 6) * 128;
    const unsigned short* Be = Bt + (size_t)e * N * K;

    __shared__ __align__(16) unsigned short ldsA[128 * 128];
    __shared__ __align__(16) unsigned short ldsB[128 * 128];

    int tid = threadIdx.x;
    int w = tid >> 6, l = tid & 63;
    int wm = w & 1, wn = w >> 1;
    int quad = l >> 4, l15 = l & 15;

    floatx4 zero = {0.f, 0.f, 0.f, 0.f};
    floatx4 acc[4][4];
#pragma unroll
    for (int i = 0; i < 4; i++)
#pragma unroll
        for (int j = 0; j < 4; j++) acc[i][j] = zero;

    int rl = l >> 4;
    int q  = (l & 15) ^ ((w * 4 + rl) & 15);
    int r0 = w * 4 + rl;
    const char* gA = (const char*)(A + (size_t)(m0 + r0) * K) + q * 16;
    const char* gB = (const char*)(Be + (size_t)(n0 + r0) * K) + q * 16;
    char* lA = (char*)ldsA + w * 1024;
    char* lB = (char*)ldsB + w * 1024;
    const size_t rowskip = (size_t)16 * K * 2;

    int k_lo = ks * KQ, k_hi = k_lo + KQ;
#pragma unroll 1
    for (int kc = k_lo; kc < k_hi; kc += 128) {
        const char* ga = gA + kc * 2;
        const char* gb = gB + kc * 2;
#pragma unroll
        for (int s = 0; s < 8; s++) {
            GLL(ga + s * rowskip, lA + s * 4096);
            GLL(gb + s * rowskip, lB + s * 4096);
        }
        __syncthreads();
#pragma unroll
        for (int kk = 0; kk < 4; kk++) {
            int p = (kk * 4 + quad) ^ l15;
            short8 af[4], bf[4];
#pragma unroll
            for (int i = 0; i < 4; i++)
                af[i] = *(const short8*)((const char*)ldsA + (wm * 64 + i * 16 + l15) * 256 + p * 16);
#pragma unroll
            for (int j = 0; j < 4; j++)
                bf[j] = *(const short8*)((const char*)ldsB + (wn * 64 + j * 16 + l15) * 256 + p * 16);
#pragma unroll
            for (int i = 0; i < 4; i++)
#pragma unroll
                for (int j = 0; j < 4; j++)
                    acc[i][j] = __builtin_amdgcn_mfma_f32_16x16x32_bf16(af[i], bf[j], acc[i][j], 0, 0, 0);
        }
        __syncthreads();
    }

    if (PARTIAL) {
#pragma unroll
        for (int i = 0; i < 4; i++) {
#pragma unroll
            for (int r = 0; r < 4; r++) {
                int row = m0 + wm * 64 + i * 16 + quad * 4 + r;
                size_t base = (size_t)(ks * MCAP + row) * N + n0 + wn * 64 + l15;
#pragma unroll
                for (int j = 0; j < 4; j++)
                    Pb[base + j * 16] = f2bf(acc[i][j][r]);
            }
        }
    } else {
#pragma unroll
        for (int i = 0; i < 4; i++) {
#pragma unroll
            for (int r = 0; r < 4; r++) {
                int row = m0 + wm * 64 + i * 16 + quad * 4 + r;
                int t = perm[row];
                if (t < 0) continue;
                size_t base = (size_t)t * N + n0 + wn * 64 + l15;
#pragma unroll
                for (int j = 0; j < 4; j++)
                    atomicAdd(&Of32[base + j * 16], acc[i][j][r]);
            }
        }
    }
}

// ---------------- reduce: out[t] = sum_ks Pb[ks][tinv[t]] ----------------
__global__ __launch_bounds__(256) void reduce_kernel(
        const unsigned short* __restrict__ Pb, const int* __restrict__ tinv,
        float* __restrict__ out) {
    int t = blockIdx.x;
    int m = tinv[t];
    const unsigned short* p0 = Pb + (size_t)m * D_MODEL;
    float* o = out + (size_t)t * D_MODEL;
#pragma unroll
    for (int it = 0; it < 3; it++) {
        int d = it * 256 + threadIdx.x;
        float s = 0.f;
#pragma unroll
        for (int ks = 0; ks < 4; ks++)
            s += bf2f(p0[(size_t)ks * MCAP * D_MODEL + d]);
        o[d] = s;
    }
}

extern "C" void kernel_launch(void* const* d_in, const int* in_sizes, int n_in,
                              void* d_out, int out_size, void* d_ws, size_t ws_size,
                              hipStream_t stream) {
    const float* x   = (const float*)d_in[0];
    const float* wsw = (const float*)d_in[1];
    const float* bsw = (const float*)d_in[2];
    const float* wi  = (const float*)d_in[3];
    const float* wo  = (const float*)d_in[4];
    float* out = (float*)d_out;

    char* ws = (char*)d_ws;
    int*   cnt      = (int*)(ws + 0);
    float* rps      = (float*)(ws + 32);
    int*   cursor   = (int*)(ws + 64);
    int*   astart   = (int*)(ws + 96);
    int*   tile_e   = (int*)(ws + 128);                  // 40 ints -> 288
    int*   tile_m0  = (int*)(ws + 288);                  // 40 ints -> 448
    int*   perm     = (int*)(ws + 512);                  // 20480  -> 20992
    int*   routes   = (int*)(ws + 20992);                // 16384  -> 37376
    int*   tinv     = (int*)(ws + 37376);                // 16384  -> 53760
    int*   cnt_part = (int*)(ws + 53760);                // 32768  -> 86528
    float* rps_part = (float*)(ws + 86528);              // 32768  -> 119296
    unsigned short* Xs  = (unsigned short*)(ws + 119808);  // 7,864,320  -> 7,984,128
    unsigned short* Y1  = (unsigned short*)(ws + 7984128); // 31,457,280 -> 39,441,408
    unsigned short* Wt1 = (unsigned short*)(ws + 39441408);// 37,748,736 -> 77,190,144
    unsigned short* Pb  = (unsigned short*)(ws + 77190144);// 31,457,280 -> 108,647,424
    unsigned short* Wt2 = (unsigned short*)(ws + 108647424);// 37,748,736 -> 146,396,160
    const bool use_partial = ws_size >= 108647424ull;    // constants per process: graph-safe
    const bool big_ws      = ws_size >= 146396160ull;

    if (!use_partial) {
        hipMemsetAsync(ws + 512, 0xFF, MCAP * 4, stream);    // perm = -1 (atomic-path guard)
        hipMemsetAsync(out, 0, (size_t)T_TOK * D_MODEL * 4, stream);
    }

    router_kernel<<<T_TOK / 4, 256, 0, stream>>>(x, wsw, bsw, routes, cnt_part, rps_part);
    plan_kernel<<<1, 256, 0, stream>>>(cnt_part, rps_part, cnt, rps, astart, cursor,
                                       tile_e, tile_m0, out + (size_t)T_TOK * D_MODEL);
    assign_kernel<<<T_TOK / 256, 256, 0, stream>>>(routes, cursor, perm, tinv);
    gather_kernel<<<T_TOK / 4, 256, 0, stream>>>(x, tinv, Xs);

    if (big_ws) {
        // both transposes in one launch; Wt1 and Wt2 both resident
        transpose_cast_kernel<<<dim3(F_FF / 64, D_MODEL / 64, 16), 256, 0, stream>>>(wi, wo, Wt1, Wt2, 0);
        gemm1_kernel<<<dim3(F_FF / 128, MAX_TILES), 256, 0, stream>>>(Xs, Wt1, tile_e, tile_m0, Y1);
        gemm2_kernel<true><<<24 * MAX_TILES, 256, 0, stream>>>(Y1, Wt2, tile_e, tile_m0, perm, Pb, out);
        reduce_kernel<<<T_TOK, 256, 0, stream>>>(Pb, tinv, out);
    } else {
        // sequential: reuse Wt1 region for both weights
        transpose_cast_kernel<<<dim3(F_FF / 64, D_MODEL / 64, 8), 256, 0, stream>>>(wi, wo, Wt1, Wt1, 0);
        gemm1_kernel<<<dim3(F_FF / 128, MAX_TILES), 256, 0, stream>>>(Xs, Wt1, tile_e, tile_m0, Y1);
        transpose_cast_kernel<<<dim3(F_FF / 64, D_MODEL / 64, 8), 256, 0, stream>>>(wi, wo, Wt1, Wt1, 8);
        if (use_partial) {
            gemm2_kernel<true><<<24 * MAX_TILES, 256, 0, stream>>>(Y1, Wt1, tile_e, tile_m0, perm, Pb, out);
            reduce_kernel<<<T_TOK, 256, 0, stream>>>(Pb, tinv, out);
        } else {
            gemm2_kernel<false><<<24 * MAX_TILES, 256, 0, stream>>>(Y1, Wt1, tile_e, tile_m0, perm, Pb, out);
        }
    }
}